// Round 1
// baseline (1726.145 us; speedup 1.0000x reference)
//
#include <hip/hip_runtime.h>

#define BB 256
#define SS 500
#define DD 128
#define TT 499           // S-1 steps
#define MM (BB*SS)

__device__ __forceinline__ float sigm_(float x){ return 1.0f/(1.0f + __expf(-x)); }
__device__ __forceinline__ float tanh_(float x){ return 1.0f - 2.0f/(1.0f + __expf(2.0f*x)); }

// Generic row-GEMM: out[m,d] = sum_seg sum_k A_seg[m,k] * W[d, col0 + seg*128 + k] + bias[d]
// A_seg are [M,128] fp32 row-major; W is [128, ldw] row-major. M = MM, tile 128x128, BK=32.
__global__ __launch_bounds__(256) void gemm_rows(
    const float* __restrict__ A0, const float* __restrict__ A1,
    const float* __restrict__ A2, const float* __restrict__ A3,
    int nseg, const float* __restrict__ W, int ldw, int col0,
    const float* __restrict__ bias, float* __restrict__ out)
{
    __shared__ float As[32][DD+4];   // [k][row]
    __shared__ float Ws[32][DD+4];   // [k][col]
    const float* srcs[4] = {A0, A1, A2, A3};
    const int m0  = blockIdx.x * 128;
    const int tid = threadIdx.x;
    const int rt  = tid >> 4;        // 0..15 -> rows rt*8..rt*8+7
    const int ct  = tid & 15;        // 0..15 -> cols ct*8..ct*8+7
    const int srow = tid >> 1;       // 0..127 staging row/col
    const int skp  = (tid & 1) * 16; // 0/16 staging k-offset

    float acc[8][8];
    #pragma unroll
    for (int r=0;r<8;++r)
        #pragma unroll
        for (int c=0;c<8;++c) acc[r][c]=0.f;

    for (int seg = 0; seg < nseg; ++seg) {
        const float* __restrict__ A = srcs[seg];
        for (int kc = 0; kc < DD; kc += 32) {
            const float* ap = A + (size_t)(m0 + srow)*DD + kc + skp;
            float4 av[4];
            av[0] = *(const float4*)(ap+0);
            av[1] = *(const float4*)(ap+4);
            av[2] = *(const float4*)(ap+8);
            av[3] = *(const float4*)(ap+12);
            const float* wp = W + (size_t)srow*ldw + col0 + seg*DD + kc + skp;
            float4 wv[4];
            wv[0] = *(const float4*)(wp+0);
            wv[1] = *(const float4*)(wp+4);
            wv[2] = *(const float4*)(wp+8);
            wv[3] = *(const float4*)(wp+12);
            __syncthreads();   // previous chunk's compute done before overwrite
            #pragma unroll
            for (int i=0;i<4;++i){
                As[skp+4*i+0][srow] = av[i].x;
                As[skp+4*i+1][srow] = av[i].y;
                As[skp+4*i+2][srow] = av[i].z;
                As[skp+4*i+3][srow] = av[i].w;
                Ws[skp+4*i+0][srow] = wv[i].x;
                Ws[skp+4*i+1][srow] = wv[i].y;
                Ws[skp+4*i+2][srow] = wv[i].z;
                Ws[skp+4*i+3][srow] = wv[i].w;
            }
            __syncthreads();
            #pragma unroll
            for (int k=0;k<32;++k){
                float a[8], w[8];
                *(float4*)&a[0] = *(const float4*)&As[k][rt*8+0];
                *(float4*)&a[4] = *(const float4*)&As[k][rt*8+4];
                *(float4*)&w[0] = *(const float4*)&Ws[k][ct*8+0];
                *(float4*)&w[4] = *(const float4*)&Ws[k][ct*8+4];
                #pragma unroll
                for (int r=0;r<8;++r)
                    #pragma unroll
                    for (int c=0;c<8;++c)
                        acc[r][c] = fmaf(a[r], w[c], acc[r][c]);
            }
        }
    }
    float bv[8];
    #pragma unroll
    for (int c=0;c<8;++c) bv[c] = bias[ct*8+c];
    #pragma unroll
    for (int r=0;r<8;++r){
        float* op = out + (size_t)(m0 + rt*8 + r)*DD + ct*8;
        float4 v0, v1;
        v0.x=acc[r][0]+bv[0]; v0.y=acc[r][1]+bv[1]; v0.z=acc[r][2]+bv[2]; v0.w=acc[r][3]+bv[3];
        v1.x=acc[r][4]+bv[4]; v1.y=acc[r][5]+bv[5]; v1.z=acc[r][6]+bv[6]; v1.w=acc[r][7]+bv[7];
        *(float4*)(op+0)=v0; *(float4*)(op+4)=v1;
    }
}

// Sequential scan: one block per batch row. 512 threads: q = tid&3 (input quarter),
// idx = tid>>2 (output dim). Each thread holds 5 quarter-rows of the recurrent
// weight matrices in registers (full fp32): W_sdf1, W_sdf2, W_pka1[:, :D],
// W_pka2[:, :D], W_ki[:, :D].
__global__ __launch_bounds__(512, 2) void dimkt_seq(
    const float* __restrict__ x_all, const float* __restrict__ cp1,
    const float* __restrict__ cp2,  const float* __restrict__ cki,
    const float* __restrict__ h0,
    const float* __restrict__ Wsdf1, const float* __restrict__ Wsdf2,
    const float* __restrict__ Wp1,   const float* __restrict__ Wp2,
    const float* __restrict__ Wki,
    const float* __restrict__ bsdf1, const float* __restrict__ bsdf2,
    float* __restrict__ out)
{
    const int b    = blockIdx.x;
    const int tid  = threadIdx.x;
    const int q    = tid & 3;
    const int idx  = tid >> 2;
    const int lane = tid & 63;
    const int wave = tid >> 6;

    // ---- weights to registers (static indexing only; fully unrolled) ----
    float w0[32], w1[32], w2[32], w3[32], w4[32];
    {
        const float* p0 = Wsdf1 + (size_t)idx*DD     + q*32;
        const float* p1 = Wsdf2 + (size_t)idx*DD     + q*32;
        const float* p2 = Wp1   + (size_t)idx*(2*DD) + q*32;  // cols 0..127 (sdf part)
        const float* p3 = Wp2   + (size_t)idx*(2*DD) + q*32;
        const float* p4 = Wki   + (size_t)idx*(4*DD) + q*32;  // cols 0..127 (h part)
        #pragma unroll
        for (int j=0;j<32;j+=4){
            *(float4*)&w0[j] = *(const float4*)&p0[j];
            *(float4*)&w1[j] = *(const float4*)&p1[j];
            *(float4*)&w2[j] = *(const float4*)&p2[j];
            *(float4*)&w3[j] = *(const float4*)&p3[j];
            *(float4*)&w4[j] = *(const float4*)&p4[j];
        }
    }
    const float b1r = bsdf1[idx];
    const float b2r = bsdf2[idx];

    __shared__ float h_s[DD];
    __shared__ float sdf_s[DD];
    __shared__ float stage_s[5*DD];   // xt | xn | cp1 | cp2 | cki
    __shared__ float yred[8];

    if (tid < DD) h_s[tid] = h0[(size_t)b*DD + tid];

    const size_t rowbase = (size_t)b * SS * DD;

    // per-step staged global rows, double-buffered in registers
    float st0 = 0.f, st1 = 0.f;
    {
        const int arr = tid >> 7, off = tid & 127;
        const size_t r0 = rowbase; // t = 0
        if      (arr == 0) st0 = x_all[r0 + off];
        else if (arr == 1) st0 = x_all[r0 + DD + off];
        else if (arr == 2) st0 = cp1[r0 + off];
        else               st0 = cp2[r0 + off];
        if (tid < DD) st1 = cki[r0 + tid];
    }

    for (int t = 0; t < TT; ++t) {
        // publish staged rows for step t
        stage_s[tid] = st0;
        if (tid < DD) stage_s[4*DD + tid] = st1;
        __syncthreads();                                    // S1

        // prefetch rows for step t+1 (latency hidden under compute)
        if (t + 1 < TT) {
            const int arr = tid >> 7, off = tid & 127;
            const size_t r = rowbase + (size_t)(t+1)*DD;
            if      (arr == 0) st0 = x_all[r + off];
            else if (arr == 1) st0 = x_all[r + DD + off];
            else if (arr == 2) st0 = cp1[r + off];
            else               st0 = cp2[r + off];
            if (tid < DD) st1 = cki[r + tid];
        }

        const float* xt_s  = stage_s;
        const float* xn_s  = stage_s + DD;
        const float* cp1_s = stage_s + 2*DD;
        const float* cp2_s = stage_s + 3*DD;
        const float* cki_s = stage_s + 4*DD;

        // ---- phase 1: o_sdf1, o_sdf2 (input x_t - h), o_ki (input h) ----
        float a0 = 0.f, a1 = 0.f, a4 = 0.f;
        #pragma unroll
        for (int j0 = 0; j0 < 32; j0 += 8) {
            float hh[8], xx[8];
            *(float4*)&hh[0] = *(const float4*)&h_s[q*32 + j0];
            *(float4*)&hh[4] = *(const float4*)&h_s[q*32 + j0 + 4];
            *(float4*)&xx[0] = *(const float4*)&xt_s[q*32 + j0];
            *(float4*)&xx[4] = *(const float4*)&xt_s[q*32 + j0 + 4];
            #pragma unroll
            for (int j = 0; j < 8; ++j) {
                const float u = xx[j] - hh[j];
                a0 = fmaf(w0[j0+j], u, a0);
                a1 = fmaf(w1[j0+j], u, a1);
                a4 = fmaf(w4[j0+j], hh[j], a4);
            }
        }
        a0 += __shfl_xor(a0, 1); a0 += __shfl_xor(a0, 2);
        a1 += __shfl_xor(a1, 1); a1 += __shfl_xor(a1, 2);
        a4 += __shfl_xor(a4, 1); a4 += __shfl_xor(a4, 2);

        const float sdfv  = sigm_(a0 + b1r) * tanh_(a1 + b2r);
        const float gamma = sigm_(a4 + cki_s[idx]);   // cki includes b_ki
        if (q == 0) sdf_s[idx] = sdfv;
        __syncthreads();                                    // S2

        // ---- phase 2: o_pka1, o_pka2 (input sdf) ----
        float a2 = 0.f, a3 = 0.f;
        #pragma unroll
        for (int j0 = 0; j0 < 32; j0 += 8) {
            float ss[8];
            *(float4*)&ss[0] = *(const float4*)&sdf_s[q*32 + j0];
            *(float4*)&ss[4] = *(const float4*)&sdf_s[q*32 + j0 + 4];
            #pragma unroll
            for (int j = 0; j < 8; ++j) {
                a2 = fmaf(w2[j0+j], ss[j], a2);
                a3 = fmaf(w3[j0+j], ss[j], a3);
            }
        }
        a2 += __shfl_xor(a2, 1); a2 += __shfl_xor(a2, 2);
        a3 += __shfl_xor(a3, 1); a3 += __shfl_xor(a3, 2);

        const float pka  = sigm_(a2 + cp1_s[idx]) * tanh_(a3 + cp2_s[idx]); // cp* include biases
        const float hpre = h_s[idx];
        const float hnew = fmaf(gamma, hpre - pka, pka);  // g*h + (1-g)*pka

        float yp = (q == 0) ? xn_s[idx] * hnew : 0.f;
        #pragma unroll
        for (int s = 1; s < 64; s <<= 1) yp += __shfl_xor(yp, s);
        if (lane == 0) yred[wave] = yp;
        __syncthreads();                                    // S3

        if (q == 0) h_s[idx] = hnew;                        // all readers of old h done
        if (tid == 0) {
            const float ysum = yred[0]+yred[1]+yred[2]+yred[3]
                             + yred[4]+yred[5]+yred[6]+yred[7];
            out[(size_t)b*TT + t] = sigm_(ysum);
        }
        // next S1 orders h_s/stage writes vs next step's reads
    }
}

extern "C" void kernel_launch(void* const* d_in, const int* in_sizes, int n_in,
                              void* d_out, int out_size, void* d_ws, size_t ws_size,
                              hipStream_t stream)
{
    (void)in_sizes; (void)n_in; (void)out_size; (void)ws_size;
    const float* qe   = (const float*)d_in[0];
    const float* ce   = (const float*)d_in[1];
    const float* qd   = (const float*)d_in[2];
    const float* cd   = (const float*)d_in[3];
    const float* corr = (const float*)d_in[4];
    const float* h0   = (const float*)d_in[5];
    const float* Wx   = (const float*)d_in[6];
    const float* bx   = (const float*)d_in[7];
    const float* Wsdf1= (const float*)d_in[8];
    const float* bsdf1= (const float*)d_in[9];
    const float* Wsdf2= (const float*)d_in[10];
    const float* bsdf2= (const float*)d_in[11];
    const float* Wp1  = (const float*)d_in[12];
    const float* bp1  = (const float*)d_in[13];
    const float* Wp2  = (const float*)d_in[14];
    const float* bp2  = (const float*)d_in[15];
    const float* Wki  = (const float*)d_in[16];
    const float* bki  = (const float*)d_in[17];
    float* out = (float*)d_out;

    float* ws    = (float*)d_ws;
    float* x_all = ws;                          // MM*DD fp32
    float* cp1   = x_all + (size_t)MM*DD;
    float* cp2   = cp1   + (size_t)MM*DD;
    float* ckiw  = cp2   + (size_t)MM*DD;       // total 262.1 MB

    dim3 g(MM/128), blk(256);
    // x_all = [q|c|qd|cd] @ Wx^T + bx
    hipLaunchKernelGGL(gemm_rows, g, blk, 0, stream, qe, ce, qd, cd, 4, Wx, 4*DD, 0,  bx,  x_all);
    // cpka1 = corr @ W_pka1[:,D:]^T + b_pka1 ; cpka2 likewise
    hipLaunchKernelGGL(gemm_rows, g, blk, 0, stream, corr, nullptr, nullptr, nullptr, 1, Wp1, 2*DD, DD, bp1, cp1);
    hipLaunchKernelGGL(gemm_rows, g, blk, 0, stream, corr, nullptr, nullptr, nullptr, 1, Wp2, 2*DD, DD, bp2, cp2);
    // cki = [corr|qd|cd] @ W_ki[:,D:]^T + b_ki
    hipLaunchKernelGGL(gemm_rows, g, blk, 0, stream, corr, qd, cd, nullptr, 3, Wki, 4*DD, DD, bki, ckiw);
    // sequential scan, one block per batch row
    hipLaunchKernelGGL(dimkt_seq, dim3(BB), dim3(512), 0, stream,
                       x_all, cp1, cp2, ckiw, h0,
                       Wsdf1, Wsdf2, Wp1, Wp2, Wki, bsdf1, bsdf2, out);
}